// Round 5
// baseline (382.479 us; speedup 1.0000x reference)
//
#include <hip/hip_runtime.h>
#include <stdint.h>
#include <stddef.h>

#define HIN 128
#define WIN 128
#define CINC 64
#define COUTC 128
#define HO 126
#define WO 126
#define HP 63
#define WP 63
#define NB 32
#define NG 16

typedef __bf16 bf16x8 __attribute__((ext_vector_type(8)));
typedef float f32x16 __attribute__((ext_vector_type(16)));

#define AS1U(p) ((const __attribute__((address_space(1))) unsigned int*)(p))
#define AS3U(p) ((__attribute__((address_space(3))) unsigned int*)(p))

__device__ __forceinline__ unsigned int f2bf(float f) {
  unsigned int u = __float_as_uint(f);
  return (u + 0x7fffu + ((u >> 16) & 1u)) >> 16;   // RNE
}

// ---- weights: w[co][cin][kh][kw] fp32 -> wt2 bf16, dword idx = step*1024 +
// khalf*512 + co*4 where step = tap*4+ks.  L2-resident (147 KB).
// Also zeroes the stats workspace.
__global__ __launch_bounds__(256) void wtrans_k(const float* __restrict__ w,
                                                unsigned short* __restrict__ wt2,
                                                float* __restrict__ stats) {
  int i = blockIdx.x * 256 + threadIdx.x;
  if (i < 1024) stats[i] = 0.0f;
  if (i >= 73728) return;
  int j = i & 7;
  int co = (i >> 3) & 127;
  int th = i >> 10;                 // [0,72)
  int half = th & 1, ks = (th >> 1) & 3, tap = th >> 3;
  int kh = tap / 3, kw = tap - 3 * kh;
  int cin = ks * 16 + half * 8 + j;
  float v = w[((co * CINC + cin) * 3 + kh) * 3 + kw];
  wt2[i] = (unsigned short)f2bf(v);
}

// ---- conv implicit-GEMM ----
// R5 = R4's occupancy geometry on R3's PROVEN sync protocol.
// grid (128, 32): 16 th x 8 tw tiles of 8 px rows x 16 px cols; block 256 =
// 4 waves; wave (wh,wc) owns 4 px rows x 16 cols x 64 co; acc[2][2] = 64 AGPR
// -> combined regs ~135 -> 3 blocks/CU = 12 waves/CU (R0-R3 were reg-capped
// at 2 blocks/CU with every pipe <20% busy = exposed latency).
// Weights: block-cooperative global_load_lds, ONE 16B-op/wave/step (4 KB/step)
// into a 4-slot ring; per step: issue j+2, s_waitcnt vmcnt(2) (counted, never
// a drain until tail), s_barrier, sched_barrier(0), then ds_read+MFMA.
// This is exactly R3's verified ordering (R4's barrier-free per-wave rings
// failed correctness; sync edits stay on proven templates).
// Block-uniform tap rotation ((bx+by)%9) spreads L2 hot lines.
// Pooled 2x2 raw max routed through x_lds after the loop.
// Raw-max-before-affine valid: A = rstd*gn_w*scale > 0.
__global__ __launch_bounds__(256, 3) void conv_k(const float* __restrict__ x,
                                                 const unsigned short* __restrict__ wt2,
                                                 const float* __restrict__ conv_b,
                                                 float* __restrict__ out,
                                                 float* __restrict__ stats) {
  __shared__ __align__(16) unsigned int x_lds[10 * 18 * 32];  // 23040 B, XOR-swizzled
  __shared__ __align__(16) unsigned int w_lds[4096];          // 16384 B: 4 slots x 1024 dw

  int t = threadIdx.x;
  int lane = t & 63, wave = t >> 6;
  int wh = wave >> 1, wc = wave & 1;               // px-half / co-half of this wave
  int tw = blockIdx.x & 7, th = blockIdx.x >> 3;   // tw 0..7, th 0..15
  int b = blockIdx.y;
  int oh0 = th * 8, ow0 = tw * 16;
  int half = lane >> 5, m = lane & 31;
  int rot4 = (((int)blockIdx.x + b) % 9) * 4;      // block-uniform tap rotation
  const unsigned int* wg = (const unsigned int*)wt2;  // dword view

  // prologue: steps 0,1 of rotated sequence -> slots 0,1 (drained at staging barrier)
#pragma unroll
  for (int j = 0; j < 2; ++j) {
    int rs = j + rot4;
    if (rs >= 36) rs -= 36;
    __builtin_amdgcn_global_load_lds(AS1U(wg + rs * 1024 + wave * 256 + lane * 4),
                                     AS3U(&w_lds[j * 1024 + wave * 256]), 16, 0, 0);
  }

  float bias[2];
#pragma unroll
  for (int nt = 0; nt < 2; ++nt) bias[nt] = conv_b[wc * 64 + nt * 32 + m];

  // ---- x staging: fp32 NCHW -> bf16 ci-pair dwords, swizzle d = p ^ ((c&7)<<2) ----
  // 10 rows x 18 cols x 32 ci-pairs = 1600 items.
  const float* xb = x + (size_t)b * CINC * HIN * WIN;
#pragma unroll
  for (int k = 0; k < 7; ++k) {
    int i = k * 256 + t;
    if (i < 1600) {
      int c4 = i % 5;
      int j = i / 5;
      int p = j & 31;          // cipair: ci = 2p, 2p+1
      int r = j >> 5;          // 0..9
      int gr = oh0 + r;
      int gc0 = ow0 + c4 * 4;
      float4 v0 = make_float4(0.f, 0.f, 0.f, 0.f);
      float4 v1 = v0;
      if (gr < HIN && gc0 < WIN) {
        const float* base = xb + ((size_t)(2 * p) * HIN + gr) * WIN + gc0;
        v0 = *(const float4*)base;
        v1 = *(const float4*)(base + HIN * WIN);
      }
      float e0[4] = {v0.x, v0.y, v0.z, v0.w};
      float e1[4] = {v1.x, v1.y, v1.z, v1.w};
#pragma unroll
      for (int cc = 0; cc < 4; ++cc) {
        int c = c4 * 4 + cc;
        if (c < 18) {
          unsigned int d = f2bf(e0[cc]) | (f2bf(e1[cc]) << 16);
          x_lds[(r * 18 + c) * 32 + (p ^ ((c & 7) << 2))] = d;
        }
      }
    }
  }
  __syncthreads();   // x ready + ring slots 0,1 landed (full drain, once)

  // ---- MFMA main loop: 36 ks-steps, cooperative 4-slot ring, counted vmcnt ----
  f32x16 acc[2][2];
#pragma unroll
  for (int nt = 0; nt < 2; ++nt)
#pragma unroll
    for (int mt = 0; mt < 2; ++mt)
#pragma unroll
      for (int r = 0; r < 16; ++r) acc[mt][nt][r] = bias[nt];

  int prb = wh * 4 + (m >> 4);   // + mt*2 + kh  -> pixel row in 10
  int pcc = m & 15;              // + kw         -> pixel col in 18

#pragma unroll
  for (int j = 0; j < 36; ++j) {
    if (j + 2 < 36) {            // issue step j+2 into slot (j+2)&3
      int rs2 = j + 2 + rot4;
      if (rs2 >= 36) rs2 -= 36;
      __builtin_amdgcn_global_load_lds(
          AS1U(wg + rs2 * 1024 + wave * 256 + lane * 4),
          AS3U(&w_lds[((j + 2) & 3) * 1024 + wave * 256]), 16, 0, 0);
    }
    // counted wait: step j's op complete (mine); steps j+1, j+2 stay in flight.
    if (j < 34)
      asm volatile("s_waitcnt vmcnt(2)" ::: "memory");
    else if (j == 34)
      asm volatile("s_waitcnt vmcnt(1)" ::: "memory");
    else
      asm volatile("s_waitcnt vmcnt(0)" ::: "memory");
    __builtin_amdgcn_s_barrier();          // all 4 waves' quarters of step j landed
    __builtin_amdgcn_sched_barrier(0);     // nothing drifts above the wait+barrier

    int rs = j + rot4;
    if (rs >= 36) rs -= 36;
    int tap = rs >> 2;
    const int ks = j & 3;              // rs&3 == j&3 (rot4 % 4 == 0, 36 % 4 == 0)
    int kh = (tap * 11) >> 5;          // tap/3 for 0..8
    int kw = tap - 3 * kh;
    int c = pcc + kw;
    int swz = (c & 7) << 2;
    int ab = c * 32 + ((ks * 8 + half * 4) ^ swz);
    bf16x8 afr[2];
#pragma unroll
    for (int mt = 0; mt < 2; ++mt)
      afr[mt] = __builtin_bit_cast(
          bf16x8, *(const uint4*)&x_lds[(prb + mt * 2 + kh) * 576 + ab]);
    int wb = (j & 3) * 1024 + half * 512 + wc * 256 + m * 4;
    __builtin_amdgcn_s_setprio(1);
#pragma unroll
    for (int nt = 0; nt < 2; ++nt) {
      bf16x8 bfr = __builtin_bit_cast(bf16x8, *(const uint4*)&w_lds[wb + nt * 128]);
#pragma unroll
      for (int mt = 0; mt < 2; ++mt)
        acc[mt][nt] = __builtin_amdgcn_mfma_f32_32x32x16_bf16(afr[mt], bfr,
                                                              acc[mt][nt], 0, 0, 0);
    }
    __builtin_amdgcn_s_setprio(0);
  }

  // ---- GN partial sums (C/D mapping: row=pixel, col=cout; verified) ----
  float s[2] = {0.f, 0.f}, qs[2] = {0.f, 0.f};
#pragma unroll
  for (int nt = 0; nt < 2; ++nt) {
#pragma unroll
    for (int mt = 0; mt < 2; ++mt) {
#pragma unroll
      for (int reg = 0; reg < 16; ++reg) {
        int c16 = (reg & 3) + 4 * half + 8 * ((reg >> 2) & 1);  // pixel col in 16
        int r8 = wh * 4 + mt * 2 + (reg >> 3);                  // pixel row in 8
        if ((oh0 + r8) < HO && (ow0 + c16) < WO) {
          float v = acc[mt][nt][reg];
          s[nt] += v;
          qs[nt] += v * v;
        }
      }
    }
  }
#pragma unroll
  for (int nt = 0; nt < 2; ++nt) {
    float sv = s[nt], qv = qs[nt];
    sv += __shfl_xor(sv, 32);
    qv += __shfl_xor(qv, 32);
    sv += __shfl_down(sv, 4, 8);
    qv += __shfl_down(qv, 4, 8);
    sv += __shfl_down(sv, 2, 8);
    qv += __shfl_down(qv, 2, 8);
    sv += __shfl_down(sv, 1, 8);
    qv += __shfl_down(qv, 1, 8);
    if (half == 0 && (m & 7) == 0) {
      int g = wc * 8 + nt * 4 + (m >> 3);
      atomicAdd(&stats[(b * NG + g) * 2 + 0], sv);
      atomicAdd(&stats[(b * NG + g) * 2 + 1], qv);
    }
  }

  __syncthreads();   // all waves done reading x_lds -> safe to reuse for pooled

  // ---- pooled 2x2 raw max -> x_lds (stride 34 dw/co) ----
#pragma unroll
  for (int nt = 0; nt < 2; ++nt) {
    int co = wc * 64 + nt * 32 + m;
#pragma unroll
    for (int mt = 0; mt < 2; ++mt) {
      int oh2l = wh * 2 + mt;
#pragma unroll
      for (int i = 0; i < 4; ++i) {
        int r0 = 2 * i;
        int ow2l = (i & 1) + 2 * half + 4 * (i >> 1);
        float mx = fmaxf(fmaxf(acc[mt][nt][r0], acc[mt][nt][r0 + 1]),
                         fmaxf(acc[mt][nt][r0 + 8], acc[mt][nt][r0 + 9]));
        x_lds[co * 34 + oh2l * 8 + ow2l] = __float_as_uint(mx);
      }
    }
  }
  __syncthreads();

  // ---- readback: 2 rows/thread, 8 consecutive dwords per row ----
#pragma unroll
  for (int i = 0; i < 2; ++i) {
    int row = t * 2 + i;           // row = co*4 + oh2l, 0..511
    int co = row >> 2, oh2l = row & 3;
    int oh2 = th * 4 + oh2l;
    if (oh2 < HP) {
      const uint2* src = (const uint2*)&x_lds[co * 34 + oh2l * 8];
      uint2 d0 = src[0], d1 = src[1], d2 = src[2], d3 = src[3];
      unsigned int v[8] = {d0.x, d0.y, d1.x, d1.y, d2.x, d2.y, d3.x, d3.y};
      float* ob = out + ((size_t)(b * COUTC + co) * HP + oh2) * WP + tw * 8;
      int n = (tw == 7) ? 7 : 8;   // WP = 63
#pragma unroll
      for (int e = 0; e < 8; ++e)
        if (e < n) ob[e] = __uint_as_float(v[e]);
    }
  }
}

// ---- finalize: one block per (b,c) plane; A,B computed once, pure streaming ----
__global__ __launch_bounds__(256) void fin_k(float* __restrict__ out,
                                             const float* __restrict__ stats,
                                             const float* __restrict__ gn_w,
                                             const float* __restrict__ gn_b,
                                             const float* __restrict__ scale) {
  const int plane = HP * WP;                     // 3969
  const float inv_cnt = 1.0f / (8.0f * HO * WO);
  int bc = blockIdx.x;                           // b*128 + c, grid = 4096
  int c = bc & 127, b = bc >> 7;
  int g = c >> 3;
  float su = stats[(b * NG + g) * 2 + 0];
  float sq = stats[(b * NG + g) * 2 + 1];
  float mean = su * inv_cnt;
  float var = fmaxf(sq * inv_cnt - mean * mean, 0.f);
  float rstd = rsqrtf(var + 1e-5f);
  float gw = gn_w[c], sc = scale[c];
  float A = rstd * gw * sc;
  float Bo = (gn_b[c] - mean * rstd * gw) * sc;

  float* p = out + (size_t)bc * plane;
  int t = threadIdx.x;
  int head = (4 - (bc & 3)) & 3;                 // scalars until 16B-aligned
  if (t < head) p[t] = fminf(fmaxf(fmaf(p[t], A, Bo), 0.0f), 1.0f);
  int n4 = (plane - head) >> 2;
  float4* p4 = (float4*)(p + head);
  for (int i = t; i < n4; i += 256) {
    float4 v = p4[i];
    v.x = fminf(fmaxf(fmaf(v.x, A, Bo), 0.0f), 1.0f);
    v.y = fminf(fmaxf(fmaf(v.y, A, Bo), 0.0f), 1.0f);
    v.z = fminf(fmaxf(fmaf(v.z, A, Bo), 0.0f), 1.0f);
    v.w = fminf(fmaxf(fmaf(v.w, A, Bo), 0.0f), 1.0f);
    p4[i] = v;
  }
  int done = head + (n4 << 2);
  int tail = plane - done;                       // 0..3
  if (t < tail) p[done + t] = fminf(fmaxf(fmaf(p[done + t], A, Bo), 0.0f), 1.0f);
}

// ---- launch ----
extern "C" void kernel_launch(void* const* d_in, const int* in_sizes, int n_in,
                              void* d_out, int out_size, void* d_ws, size_t ws_size,
                              hipStream_t stream) {
  const float* x      = (const float*)d_in[0];
  const float* conv_w = (const float*)d_in[1];
  const float* conv_b = (const float*)d_in[2];
  const float* gn_w   = (const float*)d_in[3];
  const float* gn_b   = (const float*)d_in[4];
  const float* scale  = (const float*)d_in[5];
  float* out = (float*)d_out;

  float* stats        = (float*)d_ws;                           // 4 KB
  unsigned short* wt2 = (unsigned short*)((char*)d_ws + 4096);  // 147456 B

  wtrans_k<<<288, 256, 0, stream>>>(conv_w, wt2, stats);

  conv_k<<<dim3(128, NB), 256, 0, stream>>>(x, wt2, conv_b, out, stats);

  fin_k<<<4096, 256, 0, stream>>>(out, stats, gn_w, gn_b, scale);
}

// Round 6
// 366.343 us; speedup vs baseline: 1.0440x; 1.0440x over previous
//
#include <hip/hip_runtime.h>
#include <stdint.h>
#include <stddef.h>

#define HIN 128
#define WIN 128
#define CINC 64
#define COUTC 128
#define HO 126
#define WO 126
#define HP 63
#define WP 63
#define NB 32
#define NG 16

typedef __bf16 bf16x8 __attribute__((ext_vector_type(8)));
typedef float f32x16 __attribute__((ext_vector_type(16)));

#define AS1U(p) ((const __attribute__((address_space(1))) unsigned int*)(p))
#define AS3U(p) ((__attribute__((address_space(3))) unsigned int*)(p))

#define WAITVM_(n) asm volatile("s_waitcnt vmcnt(" #n ")" ::: "memory")
#define WAITVM(n) WAITVM_(n)

__device__ __forceinline__ unsigned int f2bf(float f) {
  unsigned int u = __float_as_uint(f);
  return (u + 0x7fffu + ((u >> 16) & 1u)) >> 16;   // RNE
}

// ---- weights: w[co][cin][kh][kw] fp32 -> wt2 bf16, dword idx = step*1024 +
// khalf*512 + co*4 where step = tap*4+ks.  L2-resident (147 KB).
// Also zeroes the stats workspace.
__global__ __launch_bounds__(256) void wtrans_k(const float* __restrict__ w,
                                                unsigned short* __restrict__ wt2,
                                                float* __restrict__ stats) {
  int i = blockIdx.x * 256 + threadIdx.x;
  if (i < 1024) stats[i] = 0.0f;
  if (i >= 73728) return;
  int j = i & 7;
  int co = (i >> 3) & 127;
  int th = i >> 10;                 // [0,72)
  int half = th & 1, ks = (th >> 1) & 3, tap = th >> 3;
  int kh = tap / 3, kw = tap - 3 * kh;
  int cin = ks * 16 + half * 8 + j;
  float v = w[((co * CINC + cin) * 3 + kh) * 3 + kw];
  wt2[i] = (unsigned short)f2bf(v);
}

// ---- conv implicit-GEMM ----
// R6 = R5 with the main loop ROLLED (single-variable experiment).
// R0/R3/R5 (all fully unrolled, 15-25 KB straight-line main loops) are pinned
// at 206-223 us with every pipe <20% busy and a ~2700-cycle per-step chain no
// counter explains -> instruction-fetch theory: straight-line code streams
// through L1I at ~L2 latency (~25 cyc/inst ~= 2000 cyc per ~80-inst step).
// Fix: roll over 8 taps (body = 4 static ks-steps, ~700 B, I$-resident),
// peel tap 8 for the vmcnt tail. Sync protocol is R5's verified one, per step:
// issue DMA(j+2) -> s_waitcnt vmcnt(2) (counted) -> s_barrier ->
// sched_barrier(0) -> 4 ds_read + 4 MFMA (setprio-wrapped).
// Geometry (R5-verified): wave = 4 px rows x 16 cols x 64 co, acc[2][2],
// 3 blocks/CU; block-uniform tap rotation; LDS 39424 B.
// Raw-max-before-affine valid: A = rstd*gn_w*scale > 0.
__global__ __launch_bounds__(256, 3) void conv_k(const float* __restrict__ x,
                                                 const unsigned short* __restrict__ wt2,
                                                 const float* __restrict__ conv_b,
                                                 float* __restrict__ out,
                                                 float* __restrict__ stats) {
  __shared__ __align__(16) unsigned int x_lds[10 * 18 * 32];  // 23040 B, XOR-swizzled
  __shared__ __align__(16) unsigned int w_lds[4096];          // 16384 B: 4 slots x 1024 dw

  int t = threadIdx.x;
  int lane = t & 63, wave = t >> 6;
  int wh = wave >> 1, wc = wave & 1;               // px-half / co-half of this wave
  int tw = blockIdx.x & 7, th = blockIdx.x >> 3;   // tw 0..7, th 0..15
  int b = blockIdx.y;
  int oh0 = th * 8, ow0 = tw * 16;
  int half = lane >> 5, m = lane & 31;
  int rot4 = (((int)blockIdx.x + b) % 9) * 4;      // block-uniform tap rotation
  const unsigned int* wg = (const unsigned int*)wt2;  // dword view
  int wdma_src = wave * 256 + lane * 4;            // per-lane DMA src offset (dw)
  int wdma_dst = wave * 256;                       // wave-uniform LDS dst (dw)

  // prologue: steps 0,1 of rotated sequence -> slots 0,1 (drained at staging barrier)
#pragma unroll
  for (int j = 0; j < 2; ++j) {
    int rs = j + rot4;
    if (rs >= 36) rs -= 36;
    __builtin_amdgcn_global_load_lds(AS1U(wg + rs * 1024 + wdma_src),
                                     AS3U(&w_lds[j * 1024 + wdma_dst]), 16, 0, 0);
  }

  float bias[2];
#pragma unroll
  for (int nt = 0; nt < 2; ++nt) bias[nt] = conv_b[wc * 64 + nt * 32 + m];

  // ---- x staging: fp32 NCHW -> bf16 ci-pair dwords, swizzle d = p ^ ((c&7)<<2) ----
  // 10 rows x 18 cols x 32 ci-pairs = 1600 items.
  const float* xb = x + (size_t)b * CINC * HIN * WIN;
#pragma unroll
  for (int k = 0; k < 7; ++k) {
    int i = k * 256 + t;
    if (i < 1600) {
      int c4 = i % 5;
      int j = i / 5;
      int p = j & 31;          // cipair: ci = 2p, 2p+1
      int r = j >> 5;          // 0..9
      int gr = oh0 + r;
      int gc0 = ow0 + c4 * 4;
      float4 v0 = make_float4(0.f, 0.f, 0.f, 0.f);
      float4 v1 = v0;
      if (gr < HIN && gc0 < WIN) {
        const float* base = xb + ((size_t)(2 * p) * HIN + gr) * WIN + gc0;
        v0 = *(const float4*)base;
        v1 = *(const float4*)(base + HIN * WIN);
      }
      float e0[4] = {v0.x, v0.y, v0.z, v0.w};
      float e1[4] = {v1.x, v1.y, v1.z, v1.w};
#pragma unroll
      for (int cc = 0; cc < 4; ++cc) {
        int c = c4 * 4 + cc;
        if (c < 18) {
          unsigned int d = f2bf(e0[cc]) | (f2bf(e1[cc]) << 16);
          x_lds[(r * 18 + c) * 32 + (p ^ ((c & 7) << 2))] = d;
        }
      }
    }
  }
  __syncthreads();   // x ready + ring slots 0,1 landed (full drain, once)

  // ---- MFMA main loop: 36 ks-steps, cooperative 4-slot ring, counted vmcnt ----
  f32x16 acc[2][2];
#pragma unroll
  for (int nt = 0; nt < 2; ++nt)
#pragma unroll
    for (int mt = 0; mt < 2; ++mt)
#pragma unroll
      for (int r = 0; r < 16; ++r) acc[mt][nt][r] = bias[nt];

  int prb = wh * 4 + (m >> 4);   // + mt*2 + kh  -> pixel row in 10
  int pcc = m & 15;              // + kw         -> pixel col in 18
  int h4 = half * 4;
  int wbl = half * 512 + wc * 256 + m * 4;   // lane part of B-read addr (dw)

  // One ks-step. SLOT/DSLOT/vmcnt are compile-time; rs2/ra0/ra1/cb runtime.
#define CONV_KS(ks_, VM, DO_DMA)                                               \
  {                                                                            \
    if (DO_DMA) {                                                              \
      int rs2 = rsb + (ks_) + 2;                                               \
      if (rs2 >= 36) rs2 -= 36;                                                \
      __builtin_amdgcn_global_load_lds(                                        \
          AS1U(wg + rs2 * 1024 + wdma_src),                                    \
          AS3U(&w_lds[(((ks_) + 2) & 3) * 1024 + wdma_dst]), 16, 0, 0);        \
    }                                                                          \
    WAITVM(VM);                                                                \
    __builtin_amdgcn_s_barrier();                                              \
    __builtin_amdgcn_sched_barrier(0);                                         \
    int ax = ((ks_)*8 + h4) ^ swz;                                             \
    bf16x8 afr0 = __builtin_bit_cast(bf16x8, *(const uint4*)&x_lds[ra0 + ax]); \
    bf16x8 afr1 = __builtin_bit_cast(bf16x8, *(const uint4*)&x_lds[ra1 + ax]); \
    int wb = (ks_)*1024 + wbl;                                                 \
    bf16x8 bfr0 = __builtin_bit_cast(bf16x8, *(const uint4*)&w_lds[wb]);       \
    bf16x8 bfr1 = __builtin_bit_cast(bf16x8, *(const uint4*)&w_lds[wb + 128]); \
    __builtin_amdgcn_s_setprio(1);                                             \
    acc[0][0] = __builtin_amdgcn_mfma_f32_32x32x16_bf16(afr0, bfr0, acc[0][0], 0, 0, 0); \
    acc[1][0] = __builtin_amdgcn_mfma_f32_32x32x16_bf16(afr1, bfr0, acc[1][0], 0, 0, 0); \
    acc[0][1] = __builtin_amdgcn_mfma_f32_32x32x16_bf16(afr0, bfr1, acc[0][1], 0, 0, 0); \
    acc[1][1] = __builtin_amdgcn_mfma_f32_32x32x16_bf16(afr1, bfr1, acc[1][1], 0, 0, 0); \
    __builtin_amdgcn_s_setprio(0);                                             \
  }

#pragma unroll 1
  for (int tp = 0; tp < 8; ++tp) {   // taps 0..7 ROLLED: ~700 B I$-resident body
    int rsb = tp * 4 + rot4;
    if (rsb >= 36) rsb -= 36;        // rsb % 4 == 0 always
    int tap = rsb >> 2;
    int kh = (tap * 11) >> 5;        // tap/3 for 0..8
    int kw = tap - 3 * kh;
    int c = pcc + kw;
    int swz = (c & 7) << 2;
    int ra0 = (prb + kh) * 576 + c * 32;
    int ra1 = ra0 + 2 * 576;
    CONV_KS(0, 2, 1)
    CONV_KS(1, 2, 1)
    CONV_KS(2, 2, 1)
    CONV_KS(3, 2, 1)
  }
  {  // peeled tap 8 (steps 32..35): DMA only for 34,35; tail waits 2,2,1,0
    int rsb = 32 + rot4;
    if (rsb >= 36) rsb -= 36;
    int tap = rsb >> 2;
    int kh = (tap * 11) >> 5;
    int kw = tap - 3 * kh;
    int c = pcc + kw;
    int swz = (c & 7) << 2;
    int ra0 = (prb + kh) * 576 + c * 32;
    int ra1 = ra0 + 2 * 576;
    CONV_KS(0, 2, 1)
    CONV_KS(1, 2, 1)
    CONV_KS(2, 1, 0)
    CONV_KS(3, 0, 0)
  }
#undef CONV_KS

  // ---- GN partial sums (C/D mapping: row=pixel, col=cout; verified) ----
  float s[2] = {0.f, 0.f}, qs[2] = {0.f, 0.f};
#pragma unroll
  for (int nt = 0; nt < 2; ++nt) {
#pragma unroll
    for (int mt = 0; mt < 2; ++mt) {
#pragma unroll
      for (int reg = 0; reg < 16; ++reg) {
        int c16 = (reg & 3) + 4 * half + 8 * ((reg >> 2) & 1);  // pixel col in 16
        int r8 = wh * 4 + mt * 2 + (reg >> 3);                  // pixel row in 8
        if ((oh0 + r8) < HO && (ow0 + c16) < WO) {
          float v = acc[mt][nt][reg];
          s[nt] += v;
          qs[nt] += v * v;
        }
      }
    }
  }
#pragma unroll
  for (int nt = 0; nt < 2; ++nt) {
    float sv = s[nt], qv = qs[nt];
    sv += __shfl_xor(sv, 32);
    qv += __shfl_xor(qv, 32);
    sv += __shfl_down(sv, 4, 8);
    qv += __shfl_down(qv, 4, 8);
    sv += __shfl_down(sv, 2, 8);
    qv += __shfl_down(qv, 2, 8);
    sv += __shfl_down(sv, 1, 8);
    qv += __shfl_down(qv, 1, 8);
    if (half == 0 && (m & 7) == 0) {
      int g = wc * 8 + nt * 4 + (m >> 3);
      atomicAdd(&stats[(b * NG + g) * 2 + 0], sv);
      atomicAdd(&stats[(b * NG + g) * 2 + 1], qv);
    }
  }

  __syncthreads();   // all waves done reading x_lds -> safe to reuse for pooled

  // ---- pooled 2x2 raw max -> x_lds (stride 34 dw/co) ----
#pragma unroll
  for (int nt = 0; nt < 2; ++nt) {
    int co = wc * 64 + nt * 32 + m;
#pragma unroll
    for (int mt = 0; mt < 2; ++mt) {
      int oh2l = wh * 2 + mt;
#pragma unroll
      for (int i = 0; i < 4; ++i) {
        int r0 = 2 * i;
        int ow2l = (i & 1) + 2 * half + 4 * (i >> 1);
        float mx = fmaxf(fmaxf(acc[mt][nt][r0], acc[mt][nt][r0 + 1]),
                         fmaxf(acc[mt][nt][r0 + 8], acc[mt][nt][r0 + 9]));
        x_lds[co * 34 + oh2l * 8 + ow2l] = __float_as_uint(mx);
      }
    }
  }
  __syncthreads();

  // ---- readback: 2 rows/thread, 8 consecutive dwords per row ----
#pragma unroll
  for (int i = 0; i < 2; ++i) {
    int row = t * 2 + i;           // row = co*4 + oh2l, 0..511
    int co = row >> 2, oh2l = row & 3;
    int oh2 = th * 4 + oh2l;
    if (oh2 < HP) {
      const uint2* src = (const uint2*)&x_lds[co * 34 + oh2l * 8];
      uint2 d0 = src[0], d1 = src[1], d2 = src[2], d3 = src[3];
      unsigned int v[8] = {d0.x, d0.y, d1.x, d1.y, d2.x, d2.y, d3.x, d3.y};
      float* ob = out + ((size_t)(b * COUTC + co) * HP + oh2) * WP + tw * 8;
      int n = (tw == 7) ? 7 : 8;   // WP = 63
#pragma unroll
      for (int e = 0; e < 8; ++e)
        if (e < n) ob[e] = __uint_as_float(v[e]);
    }
  }
}

// ---- finalize: one block per (b,c) plane; A,B computed once, pure streaming ----
__global__ __launch_bounds__(256) void fin_k(float* __restrict__ out,
                                             const float* __restrict__ stats,
                                             const float* __restrict__ gn_w,
                                             const float* __restrict__ gn_b,
                                             const float* __restrict__ scale) {
  const int plane = HP * WP;                     // 3969
  const float inv_cnt = 1.0f / (8.0f * HO * WO);
  int bc = blockIdx.x;                           // b*128 + c, grid = 4096
  int c = bc & 127, b = bc >> 7;
  int g = c >> 3;
  float su = stats[(b * NG + g) * 2 + 0];
  float sq = stats[(b * NG + g) * 2 + 1];
  float mean = su * inv_cnt;
  float var = fmaxf(sq * inv_cnt - mean * mean, 0.f);
  float rstd = rsqrtf(var + 1e-5f);
  float gw = gn_w[c], sc = scale[c];
  float A = rstd * gw * sc;
  float Bo = (gn_b[c] - mean * rstd * gw) * sc;

  float* p = out + (size_t)bc * plane;
  int t = threadIdx.x;
  int head = (4 - (bc & 3)) & 3;                 // scalars until 16B-aligned
  if (t < head) p[t] = fminf(fmaxf(fmaf(p[t], A, Bo), 0.0f), 1.0f);
  int n4 = (plane - head) >> 2;
  float4* p4 = (float4*)(p + head);
  for (int i = t; i < n4; i += 256) {
    float4 v = p4[i];
    v.x = fminf(fmaxf(fmaf(v.x, A, Bo), 0.0f), 1.0f);
    v.y = fminf(fmaxf(fmaf(v.y, A, Bo), 0.0f), 1.0f);
    v.z = fminf(fmaxf(fmaf(v.z, A, Bo), 0.0f), 1.0f);
    v.w = fminf(fmaxf(fmaf(v.w, A, Bo), 0.0f), 1.0f);
    p4[i] = v;
  }
  int done = head + (n4 << 2);
  int tail = plane - done;                       // 0..3
  if (t < tail) p[done + t] = fminf(fmaxf(fmaf(p[done + t], A, Bo), 0.0f), 1.0f);
}

// ---- launch ----
extern "C" void kernel_launch(void* const* d_in, const int* in_sizes, int n_in,
                              void* d_out, int out_size, void* d_ws, size_t ws_size,
                              hipStream_t stream) {
  const float* x      = (const float*)d_in[0];
  const float* conv_w = (const float*)d_in[1];
  const float* conv_b = (const float*)d_in[2];
  const float* gn_w   = (const float*)d_in[3];
  const float* gn_b   = (const float*)d_in[4];
  const float* scale  = (const float*)d_in[5];
  float* out = (float*)d_out;

  float* stats        = (float*)d_ws;                           // 4 KB
  unsigned short* wt2 = (unsigned short*)((char*)d_ws + 4096);  // 147456 B

  wtrans_k<<<288, 256, 0, stream>>>(conv_w, wt2, stats);

  conv_k<<<dim3(128, NB), 256, 0, stream>>>(x, wt2, conv_b, out, stats);

  fin_k<<<4096, 256, 0, stream>>>(out, stats, gn_w, gn_b, scale);
}